// Round 9
// baseline (188.937 us; speedup 1.0000x reference)
//
#include <hip/hip_runtime.h>
#include <math.h>

// ---------------------------------------------------------------------------
// LTFGW: N=4096, K=16 (k1=17), T=16, NT=16, D=128, OUTER=3, INNER=5.
//
// R14: Pareto recombination from the 9-experiment ledger.
//   total = F(~72us fixed) + adj-scatter + main-body.
//   - main-body floor = R5's 71.5us (unconditional if-converted body,
//     C1 via SCALAR loads from precomputed C1ws, near-empty prologue).
//     Every alternative C1 delivery measured worse (branchy 80, cselect 92,
//     LDS table 545 [spill], in-main gather 92).
//   - adj scatter costs ~20-38us wherever it lives; SYMMETRIC gather
//     (R13-proven: FETCH 92->57MB) halves it.
//   New: R5-exact main + symmetric c1gather in prep (153 loads/node, write
//   both mirror entries) + c1gather blocks FIRST in the fused grid so the
//   latency-bound scatter floods memory before VALU-bound pgemm occupies
//   the CUs. cc1/mask epilogue R0-exact (bit-identical numerics).
// R9  (kept): 32x64 pgemm tiles.
// R2/R3 lesson (kept): C1 into main via scalar/SGPR path only.
// ---------------------------------------------------------------------------

#define NN 4096
#define KNB 16
#define K1 17
#define C1STRIDE 20   // C1 row: 17 vals + cc1@17 + mask@18(row0) + pad
#define C1NODE 340
#define TSTR 296      // Ksh per-template stride; 296%32==8 -> 2-way banks
#define TINYF 1e-16f

typedef const __attribute__((address_space(4))) float* c4fp;
typedef const __attribute__((address_space(4))) int*   c4ip;
__device__ __forceinline__ float sload(const float* p){ return *(c4fp)(unsigned long long)p; }
__device__ __forceinline__ int   sloadi(const int* p) { return *(c4ip)(unsigned long long)p; }

template<int CTRL>
__device__ __forceinline__ float dppmov(float x) {
  return __int_as_float(
      __builtin_amdgcn_update_dpp(0, __float_as_int(x), CTRL, 0xF, 0xF, true));
}
__device__ __forceinline__ float xor4v(float x) {        // xor4 = xor7 then xor3
  return dppmov<0x1B>(dppmov<0x141>(x));
}
__device__ __forceinline__ float rsum16(float x) {
  x += dppmov<0xB1>(x); x += dppmov<0x4E>(x);
  x += xor4v(x);        x += dppmov<0x128>(x);
  return x;
}
__device__ __forceinline__ float rmin16(float x) {
  x = fminf(x, dppmov<0xB1>(x)); x = fminf(x, dppmov<0x4E>(x));
  x = fminf(x, xor4v(x));        x = fminf(x, dppmov<0x128>(x));
  return x;
}
__device__ __forceinline__ float rmax16(float x) {
  x = fmaxf(x, dppmov<0xB1>(x)); x = fmaxf(x, dppmov<0x4E>(x));
  x = fmaxf(x, xor4v(x));        x = fmaxf(x, dppmov<0x128>(x));
  return x;
}
__device__ __forceinline__ float rcpn(float x) {   // rcp + 1 Newton step
  float r = __builtin_amdgcn_rcpf(x);
  return r * (2.f - x * r);
}

// cumulative XOR walk (verified R1/R4, absmax 0): after step r, g = src lane l^r
#define WSTEP(C, R) { g = dppmov<C>(g); acc = fmaf(g, c2reg[R], acc); }
#define WALK15() \
  WSTEP(0xB1,1)  WSTEP(0x1B,2)  WSTEP(0xB1,3)  WSTEP(0x141,4) \
  WSTEP(0xB1,5)  WSTEP(0x1B,6)  WSTEP(0xB1,7)  WSTEP(0x140,8) \
  WSTEP(0xB1,9)  WSTEP(0x1B,10) WSTEP(0xB1,11) WSTEP(0x141,12) \
  WSTEP(0xB1,13) WSTEP(0x1B,14) WSTEP(0xB1,15)

// ---------------------------------------------------------------------------
// prep_combined: one dispatch, block-range partitioned. c1gather FIRST so
// the latency-bound scatter issues before pgemm's VALU work fills the CUs.
//   blocks [0,4096)       : c1gather_sym -> C1ws floats + cc1 + mask
//   blocks [4096,4608)    : pgemm  P = x @ tf^T   (32x64 tile)
//   blocks [4608,5632)    : xsq[n] = ||x[n]||^2
//   block  5632           : scalars (alpha,q,cq,tfsq)
// ---------------------------------------------------------------------------
#define PG_C1    4096
#define PG_GEMM  (PG_C1 + 512)           // 4608
#define PG_XSQ   (PG_GEMM + 1024)        // 5632
#define PG_SCAL  PG_XSQ                  // block 5632
#define PG_TOT   (PG_SCAL + 1)           // 5633

__global__ __launch_bounds__(256) void prep_combined(
    const float* __restrict__ x, const float* __restrict__ adj,
    const int* __restrict__ neighbors, const float* __restrict__ templates_,
    const float* __restrict__ tf, const float* __restrict__ q0,
    const float* __restrict__ alpha0,
    float* __restrict__ P, float* __restrict__ C1ws, float* __restrict__ xsq,
    float* __restrict__ tfsq, float* __restrict__ qmat, float* __restrict__ cq,
    float* __restrict__ walpha) {
  __shared__ __align__(16) float smem[64*36 + 64*68];   // 26624 B arena
  const int b = blockIdx.x, tid = threadIdx.x;

  if (b < PG_C1) {
    // ---- c1gather_sym: C1 symmetric -> 153 upper-tri loads (1/thread) ----
    int n = b;
    int*   nbs  = (int*)smem;          // 17 ints
    float* c1sh = smem + 32;           // 289 floats
    if (tid < K1) nbs[tid] = (tid == 0) ? n : neighbors[n*KNB + tid - 1];
    __syncthreads();
    // upper-tri element per thread; 150 have e<256, 3 remapped onto idle
    // lower-tri tids (17->(15,15), 34->(15,16), 51->(16,16)).
    int e = tid;
    if (tid == 17)      e = 15*17 + 15;
    else if (tid == 34) e = 15*17 + 16;
    else if (tid == 51) e = 16*17 + 16;
    const int gi = e / 17, gj = e % 17;
    if (gj >= gi) {
      float v = adj[(long long)nbs[gi] * NN + nbs[gj]];   // {0.0f,1.0f}
      c1sh[gi*17 + gj] = v;
      c1sh[gj*17 + gi] = v;            // mirror (adj symmetric)
    }
    __syncthreads();
    for (int e2 = tid; e2 < 289; e2 += 256) {
      int i = e2 / 17, j = e2 % 17;
      C1ws[n*C1NODE + i*C1STRIDE + j] = c1sh[e2];
    }
    bool nz = false;
    if (tid < K1) {
      float s = 0.f;
#pragma unroll
      for (int j = 0; j < K1; ++j) {
        float v = c1sh[tid*17 + j];
        s = fmaf(v, v, s); nz |= (v != 0.f);
      }
      C1ws[n*C1NODE + tid*C1STRIDE + 17] = s * (1.f/17.f);
    }
    unsigned long long bal = __ballot(nz);   // wave 0 holds tid<17
    if (tid == 0)
      ((int*)C1ws)[n*C1NODE + 18] = (int)(bal & 0x1FFFF);
    return;
  }

  if (b < PG_GEMM) {
    // ---- pgemm: 32 rows x 64 cols per block, 2x4 per thread ----
    float (*As)[36] = (float (*)[36])smem;            // As[d][row], d<64
    float (*Bs)[68] = (float (*)[68])(smem + 64*36);  // Bs[d][col], d<64
    int bb = b - PG_C1;
    int tx = tid & 15, ty = tid >> 4;
    int r0 = (bb >> 2) * 32, c0 = (bb & 3) * 64;
    float acc[2][4] = {};
    for (int h = 0; h < 2; ++h) {
      __syncthreads();
#pragma unroll
      for (int q = 0; q < 2; ++q) {
        int f = tid + 256*q;
        int row = f >> 4, d4 = (f & 15) << 2;
        float4 a = *(const float4*)&x[(r0+row)*128 + h*64 + d4];
        As[d4+0][row]=a.x; As[d4+1][row]=a.y; As[d4+2][row]=a.z; As[d4+3][row]=a.w;
      }
#pragma unroll
      for (int q = 0; q < 4; ++q) {
        int f = tid + 256*q;
        int row = f >> 4, d4 = (f & 15) << 2;
        float4 bb4 = *(const float4*)&tf[(c0+row)*128 + h*64 + d4];
        Bs[d4+0][row]=bb4.x; Bs[d4+1][row]=bb4.y; Bs[d4+2][row]=bb4.z; Bs[d4+3][row]=bb4.w;
      }
      __syncthreads();
#pragma unroll
      for (int d = 0; d < 64; ++d) {
        float2 a = *(const float2*)&As[d][ty*2];
        float4 bb4 = *(const float4*)&Bs[d][tx*4];
        float av[2]={a.x,a.y}, bv[4]={bb4.x,bb4.y,bb4.z,bb4.w};
#pragma unroll
        for (int i = 0; i < 2; ++i)
#pragma unroll
          for (int j = 0; j < 4; ++j) acc[i][j] = fmaf(av[i], bv[j], acc[i][j]);
      }
    }
#pragma unroll
    for (int i = 0; i < 2; ++i) {
      float4 o; o.x=acc[i][0]; o.y=acc[i][1]; o.z=acc[i][2]; o.w=acc[i][3];
      *(float4*)&P[(r0 + ty*2 + i)*256 + c0 + tx*4] = o;
    }
    return;
  }

  if (b < PG_XSQ) {
    // ---- xsq: 4 rows per block, 1 wave per row ----
    int n = (b - PG_GEMM)*4 + (tid >> 6), lane = tid & 63;
    float2 v = *(const float2*)&x[n*128 + lane*2];
    float s = fmaf(v.x, v.x, v.y*v.y);
    s += __shfl_xor(s,1); s += __shfl_xor(s,2);  s += __shfl_xor(s,4);
    s += __shfl_xor(s,8); s += __shfl_xor(s,16); s += __shfl_xor(s,32);
    if (lane == 0) xsq[n] = s;
    return;
  }

  if (b == PG_SCAL) {
    // ---- scalars: alpha, q=softmax(q0), cq, tfsq ----
    int t = tid >> 4, l = tid & 15;
    if (tid == 0) walpha[0] = 1.f / (1.f + expf(-alpha0[0]));
    float qr[16]; float mx = -3.0e38f;
#pragma unroll
    for (int m = 0; m < 16; ++m) { qr[m] = q0[t*16+m]; mx = fmaxf(mx, qr[m]); }
    float s = 0.f;
#pragma unroll
    for (int m = 0; m < 16; ++m) { qr[m] = expf(qr[m]-mx); s += qr[m]; }
    float inv = 1.f / s;
    qmat[tid] = qr[l] * inv;
    float c = 0.f;
#pragma unroll
    for (int m = 0; m < 16; ++m) {
      float c2 = templates_[t*256 + l*16 + m];
      c = fmaf(qr[m]*inv, c2*c2, c);
    }
    cq[tid] = c;
    float ts = 0.f;
#pragma unroll
    for (int dq = 0; dq < 32; ++dq) {
      float4 v = *(const float4*)&tf[tid*128 + dq*4];
      ts = fmaf(v.x,v.x,ts); ts = fmaf(v.y,v.y,ts);
      ts = fmaf(v.z,v.z,ts); ts = fmaf(v.w,v.w,ts);
    }
    tfsq[tid] = ts;
    return;
  }
}

// ---------------------------------------------------------------------------
// main: 1 block/node, 256 thr = 16 templates x 16 cols (R5/R0-exact body:
// 71.5us measured — unconditional if-converted rows, scalar-pipe C1 loads).
// ---------------------------------------------------------------------------
__global__ __launch_bounds__(256, 2) void ltfgw_main(
    const float* __restrict__ P, const float* __restrict__ C1ws,
    const float* __restrict__ xsq, const float* __restrict__ tfsq,
    const float* __restrict__ qmat, const float* __restrict__ cq,
    const float* __restrict__ walpha, const int* __restrict__ neighbors,
    const float* __restrict__ templates_, float* __restrict__ out) {
  __shared__ __align__(16) float Ksh[16 * TSTR];
  __shared__ __align__(16) float Ush[256];
  __shared__ __align__(16) float Vsh[256];

  const int tid = threadIdx.x;
  const int t = tid >> 4, l = tid & 15;
  const int n = blockIdx.x;

  const float alpha = sload(walpha);
  const float oma = 1.f - alpha;
  const float na2 = -2.f * alpha;
  const int mask = sloadi((const int*)C1ws + n*C1NODE + 18);

  int nbk[K1];
  nbk[0] = n;
#pragma unroll
  for (int k = 1; k < K1; ++k) nbk[k] = sloadi(neighbors + n*KNB + (k-1));

  const float tfsq_l = tfsq[tid];
  const float cq_l   = cq[tid];
  const float q_l    = qmat[tid];

  // Mcol = (1-a)*M + a*cC ; grad = Mcol - 2a*(C1@G@C2^T)
  float Mcol[K1];
#pragma unroll
  for (int k = 0; k < K1; ++k) {
    float xs  = sload(xsq + nbk[k]);
    float cc1 = sload(C1ws + n*C1NODE + k*C1STRIDE + 17);
    float pv  = P[nbk[k]*256 + tid];
    Mcol[k] = oma * (xs + tfsq_l - 2.f*pv) + alpha * (cc1 + cq_l);
  }

  // c2reg[r] = -2a * C2[t][l][l^r]  (pre-rotated for the XOR walk)
  float c2reg[16];
#pragma unroll
  for (int r = 0; r < 16; ++r)
    c2reg[r] = na2 * templates_[t*256 + l*16 + (l ^ r)];

  // G[j][l] in registers; init p*q
  float Gcol[K1];
#pragma unroll
  for (int j = 0; j < K1; ++j) Gcol[j] = (1.f/17.f) * q_l;

  const int tb = t * TSTR;
  float ur[16], u16 = 0.f, vm = 1.f;

#pragma unroll 1
  for (int outer = 0; outer < 3; ++outer) {
    // grad rows -> Kc[]; only C1-nonzero rows get the matvec + DPP walk
    float Kc[K1];
    float lo = 3.0e38f, hi = -3.0e38f;
#pragma unroll
    for (int i = 0; i < K1; ++i) {
      float gr = Mcol[i];
      if (mask & (1 << i)) {
        const float* c1r = C1ws + n*C1NODE + i*C1STRIDE;
        float s = 0.f;
#pragma unroll
        for (int j = 0; j < K1; ++j) s = fmaf(sload(c1r + j), Gcol[j], s);
        float g = s, acc = s * c2reg[0];
        WALK15()
        gr += acc;
      }
      Kc[i] = gr;
      lo = fminf(lo, gr); hi = fmaxf(hi, gr);
    }
    lo = rmin16(lo); hi = rmax16(hi);
    float eps = 0.1f * (hi - lo) + TINYF;
    float sc = 1.4426950408889634f * __builtin_amdgcn_rcpf(eps);
    float nsc = -sc, losc = lo * sc;
#pragma unroll
    for (int i = 0; i < K1; ++i) {
      Kc[i] = __builtin_amdgcn_exp2f(fmaf(Kc[i], nsc, losc));
      Ksh[tb + i*17 + l] = Kc[i];           // transpose write (same wave)
    }
    // row l of K for the u-update
    float Krow[16];
#pragma unroll
    for (int jq = 0; jq < 4; ++jq) {
      float4 v = *(const float4*)&Ksh[tb + l*17 + jq*4];
      Krow[jq*4+0]=v.x; Krow[jq*4+1]=v.y; Krow[jq*4+2]=v.z; Krow[jq*4+3]=v.w;
    }

    // Sinkhorn: 5 iters (u then v), v0 = 1
    float vlane = 1.f;
    Vsh[tid] = 1.f;
#pragma unroll 1
    for (int it = 0; it < 5; ++it) {
      float vr[16];
#pragma unroll
      for (int q = 0; q < 4; ++q) {
        float4 v = *(const float4*)&Vsh[t*16 + q*4];
        vr[q*4+0]=v.x; vr[q*4+1]=v.y; vr[q*4+2]=v.z; vr[q*4+3]=v.w;
      }
      float w = 0.f;
#pragma unroll
      for (int j = 0; j < 16; ++j) w = fmaf(Krow[j], vr[j], w);
      float w16 = rsum16(Kc[16] * vlane);          // row 16 via DPP
      float um = (1.f/17.f) * rcpn(fmaxf(w,   TINYF));
      u16      = (1.f/17.f) * rcpn(fmaxf(w16, TINYF));
      Ush[tid] = um;
#pragma unroll
      for (int q = 0; q < 4; ++q) {
        float4 v = *(const float4*)&Ush[t*16 + q*4];
        ur[q*4+0]=v.x; ur[q*4+1]=v.y; ur[q*4+2]=v.z; ur[q*4+3]=v.w;
      }
      float sg = u16 * Kc[16];
#pragma unroll
      for (int k = 0; k < 16; ++k) sg = fmaf(ur[k], Kc[k], sg);
      vlane = q_l * rcpn(fmaxf(sg, TINYF));
      Vsh[tid] = vlane;
    }
    vm = vlane;
    // G = u * K * v
#pragma unroll
    for (int k = 0; k < 16; ++k) Gcol[k] = ur[k] * Kc[k] * vm;
    Gcol[16] = u16 * Kc[16] * vm;
  }

  // out[n,t] = sum_{i,l} (Mcol + delta) * G
  float acc1 = 0.f;
#pragma unroll
  for (int i = 0; i < K1; ++i) acc1 = fmaf(Mcol[i], Gcol[i], acc1);
#pragma unroll
  for (int i = 0; i < K1; ++i) {
    if (mask & (1 << i)) {
      const float* c1r = C1ws + n*C1NODE + i*C1STRIDE;
      float s = 0.f;
#pragma unroll
      for (int j = 0; j < K1; ++j) s = fmaf(sload(c1r + j), Gcol[j], s);
      float g = s, acc = s * c2reg[0];
      WALK15()
      acc1 = fmaf(acc, Gcol[i], acc1);
    }
  }
  float accout = rsum16(acc1);
  if (l == 0) out[n*16 + t] = accout;
}

// ---------------------------------------------------------------------------
extern "C" void kernel_launch(void* const* d_in, const int* in_sizes, int n_in,
                              void* d_out, int out_size, void* d_ws, size_t ws_size,
                              hipStream_t stream) {
  const float* x          = (const float*)d_in[0];
  const float* adj        = (const float*)d_in[1];
  const int*   neighbors  = (const int*)  d_in[2];
  const float* templates_ = (const float*)d_in[3];
  const float* tfeat      = (const float*)d_in[4];
  const float* q0         = (const float*)d_in[5];
  const float* alpha0     = (const float*)d_in[6];
  float* out = (float*)d_out;

  float* ws     = (float*)d_ws;
  float* P      = ws;                       // 4096*256
  float* C1ws   = P + 4096*256;             // 4096*340
  float* xsq    = C1ws + 4096*C1NODE;       // 4096
  float* tfsq   = xsq + 4096;               // 256
  float* qmat   = tfsq + 256;               // 256
  float* cq     = qmat + 256;               // 256
  float* walpha = cq + 256;                 // 1

  hipLaunchKernelGGL(prep_combined, dim3(PG_TOT), dim3(256), 0, stream,
                     x, adj, neighbors, templates_, tfeat, q0, alpha0,
                     P, C1ws, xsq, tfsq, qmat, cq, walpha);
  hipLaunchKernelGGL(ltfgw_main, dim3(4096), dim3(256), 0, stream,
                     P, C1ws, xsq, tfsq, qmat, cq, walpha, neighbors,
                     templates_, out);
}

// Round 10
// 180.821 us; speedup vs baseline: 1.0449x; 1.0449x over previous
//
#include <hip/hip_runtime.h>
#include <math.h>

// ---------------------------------------------------------------------------
// LTFGW: N=4096, K=16 (k1=17), T=16, NT=16, D=128, OUTER=3, INNER=5.
//
// R15: model-complete ledger (10 experiments): total = F(~72 fixed) + prep +
//   main, with {scatter-in-prep: 40+73 = worst}, {bitset-prep: 25+80},
//   {scatter-in-main: 5+92 = best, 174.0}. Remaining slack: R9's adjbits
//   stream measured ~20us vs ~10-12us BW floor — its a0[tid*4+q] pattern has
//   64B lane stride (64 line-requests per instruction, 4x a coalesced one).
//   Fix: fully-coalesced float4 loads (ap[q*256+tid], lane-contiguous),
//   nibble-pack via 3-step shfl_xor OR (no LDS/atomics), 4 rows/block x
//   1024 blocks placed FIRST so the BW-bound stream floods HBM while the
//   VALU-bound pgemm fills behind. Main = R9 verbatim (bitset-L2 prologue +
//   branchy body, 80.3us measured).
// R9  (kept): 32x64 pgemm tiles; main with bitset prologue.
// R7  (kept): real uniform outer branch via volatile-asm pin on rmi.
// R6  (kept): binary adj -> packed 2MB bitset; cc1 = popcount/17.
// R2/R3 lesson (kept): no bulk LDS vector loads inside unrolled branches.
// ---------------------------------------------------------------------------

#define NN 4096
#define KNB 16
#define K1 17
#define TSTR 296      // Ksh per-template stride; 296%32==8 -> 2-way banks
#define TINYF 1e-16f

typedef const __attribute__((address_space(4))) float* c4fp;
typedef const __attribute__((address_space(4))) int*   c4ip;
__device__ __forceinline__ float sload(const float* p){ return *(c4fp)(unsigned long long)p; }
__device__ __forceinline__ int   sloadi(const int* p) { return *(c4ip)(unsigned long long)p; }

template<int CTRL>
__device__ __forceinline__ float dppmov(float x) {
  return __int_as_float(
      __builtin_amdgcn_update_dpp(0, __float_as_int(x), CTRL, 0xF, 0xF, true));
}
__device__ __forceinline__ float xor4v(float x) {        // xor4 = xor7 then xor3
  return dppmov<0x1B>(dppmov<0x141>(x));
}
__device__ __forceinline__ float rsum16(float x) {
  x += dppmov<0xB1>(x); x += dppmov<0x4E>(x);
  x += xor4v(x);        x += dppmov<0x128>(x);
  return x;
}
__device__ __forceinline__ float rmin16(float x) {
  x = fminf(x, dppmov<0xB1>(x)); x = fminf(x, dppmov<0x4E>(x));
  x = fminf(x, xor4v(x));        x = fminf(x, dppmov<0x128>(x));
  return x;
}
__device__ __forceinline__ float rmax16(float x) {
  x = fmaxf(x, dppmov<0xB1>(x)); x = fmaxf(x, dppmov<0x4E>(x));
  x = fmaxf(x, xor4v(x));        x = fmaxf(x, dppmov<0x128>(x));
  return x;
}
__device__ __forceinline__ float rcpn(float x) {   // rcp + 1 Newton step
  float r = __builtin_amdgcn_rcpf(x);
  return r * (2.f - x * r);
}

// cumulative XOR walk (verified R1/R4, absmax 0): after step r, g = src lane l^r
#define WSTEP(C, R) { g = dppmov<C>(g); acc = fmaf(g, c2reg[R], acc); }
#define WALK15() \
  WSTEP(0xB1,1)  WSTEP(0x1B,2)  WSTEP(0xB1,3)  WSTEP(0x141,4) \
  WSTEP(0xB1,5)  WSTEP(0x1B,6)  WSTEP(0xB1,7)  WSTEP(0x140,8) \
  WSTEP(0xB1,9)  WSTEP(0x1B,10) WSTEP(0xB1,11) WSTEP(0x141,12) \
  WSTEP(0xB1,13) WSTEP(0x1B,14) WSTEP(0xB1,15)

// ---------------------------------------------------------------------------
// prep_combined: one dispatch, block-range partitioned. adjbits FIRST
// (memory-bound stream floods HBM while VALU-bound pgemm fills behind).
//   blocks [0,1024)       : adjbits, 4 rows/block, coalesced + shfl pack
//   blocks [1024,1536)    : pgemm  P = x @ tf^T   (32x64 tile)
//   blocks [1536,2560)    : xsq[n] = ||x[n]||^2
//   block  2560           : scalars (alpha,q,cq,tfsq)
// ---------------------------------------------------------------------------
#define PG_ADJ   1024
#define PG_GEMM  (PG_ADJ + 512)          // 1536
#define PG_XSQ   (PG_GEMM + 1024)        // 2560
#define PG_SCAL  PG_XSQ                  // block 2560
#define PG_TOT   (PG_SCAL + 1)           // 2561

__global__ __launch_bounds__(256) void prep_combined(
    const float* __restrict__ x, const float* __restrict__ adj,
    const int* __restrict__ neighbors, const float* __restrict__ templates_,
    const float* __restrict__ tf, const float* __restrict__ q0,
    const float* __restrict__ alpha0,
    float* __restrict__ P, unsigned* __restrict__ adjbits,
    float* __restrict__ xsq,
    float* __restrict__ tfsq, float* __restrict__ qmat, float* __restrict__ cq,
    float* __restrict__ walpha) {
  __shared__ __align__(16) float smem[64*36 + 64*68];   // 26624 B arena
  const int b = blockIdx.x, tid = threadIdx.x;

  if (b < PG_ADJ) {
    // ---- adjbits: 4 adj rows per block, fully-coalesced float4 stream ----
    // f = q*256+tid covers cols 4f..4f+3 -> nibble at bit (f&7)*4 of word
    // f>>3. OR-combine nibbles across each aligned 8-lane group (shfl_xor
    // 1,2,4 stays inside the group); lane with (tid&7)==0 writes the word.
    int row0 = b * 4;
#pragma unroll
    for (int r = 0; r < 4; ++r) {
      const float4* ap = (const float4*)&adj[(long long)(row0 + r) * NN];
#pragma unroll
      for (int q = 0; q < 4; ++q) {
        float4 v = ap[q*256 + tid];              // lane-contiguous: coalesced
        unsigned nib = (unsigned)(v.x != 0.f)
                     | ((unsigned)(v.y != 0.f) << 1)
                     | ((unsigned)(v.z != 0.f) << 2)
                     | ((unsigned)(v.w != 0.f) << 3);
        unsigned m = nib << ((tid & 7) * 4);
        m |= (unsigned)__shfl_xor((int)m, 1);
        m |= (unsigned)__shfl_xor((int)m, 2);
        m |= (unsigned)__shfl_xor((int)m, 4);
        if ((tid & 7) == 0)
          adjbits[(row0 + r)*128 + (q*256 + tid)/8] = m;
      }
    }
    return;
  }

  if (b < PG_GEMM) {
    // ---- pgemm: 32 rows x 64 cols per block, 2x4 per thread ----
    float (*As)[36] = (float (*)[36])smem;            // As[d][row], d<64
    float (*Bs)[68] = (float (*)[68])(smem + 64*36);  // Bs[d][col], d<64
    int bb = b - PG_ADJ;
    int tx = tid & 15, ty = tid >> 4;
    int r0 = (bb >> 2) * 32, c0 = (bb & 3) * 64;
    float acc[2][4] = {};
    for (int h = 0; h < 2; ++h) {
      __syncthreads();
#pragma unroll
      for (int q = 0; q < 2; ++q) {
        int f = tid + 256*q;
        int row = f >> 4, d4 = (f & 15) << 2;
        float4 a = *(const float4*)&x[(r0+row)*128 + h*64 + d4];
        As[d4+0][row]=a.x; As[d4+1][row]=a.y; As[d4+2][row]=a.z; As[d4+3][row]=a.w;
      }
#pragma unroll
      for (int q = 0; q < 4; ++q) {
        int f = tid + 256*q;
        int row = f >> 4, d4 = (f & 15) << 2;
        float4 bb4 = *(const float4*)&tf[(c0+row)*128 + h*64 + d4];
        Bs[d4+0][row]=bb4.x; Bs[d4+1][row]=bb4.y; Bs[d4+2][row]=bb4.z; Bs[d4+3][row]=bb4.w;
      }
      __syncthreads();
#pragma unroll
      for (int d = 0; d < 64; ++d) {
        float2 a = *(const float2*)&As[d][ty*2];
        float4 bb4 = *(const float4*)&Bs[d][tx*4];
        float av[2]={a.x,a.y}, bv[4]={bb4.x,bb4.y,bb4.z,bb4.w};
#pragma unroll
        for (int i = 0; i < 2; ++i)
#pragma unroll
          for (int j = 0; j < 4; ++j) acc[i][j] = fmaf(av[i], bv[j], acc[i][j]);
      }
    }
#pragma unroll
    for (int i = 0; i < 2; ++i) {
      float4 o; o.x=acc[i][0]; o.y=acc[i][1]; o.z=acc[i][2]; o.w=acc[i][3];
      *(float4*)&P[(r0 + ty*2 + i)*256 + c0 + tx*4] = o;
    }
    return;
  }

  if (b < PG_XSQ) {
    // ---- xsq: 4 rows per block, 1 wave per row ----
    int n = (b - PG_GEMM)*4 + (tid >> 6), lane = tid & 63;
    float2 v = *(const float2*)&x[n*128 + lane*2];
    float s = fmaf(v.x, v.x, v.y*v.y);
    s += __shfl_xor(s,1); s += __shfl_xor(s,2);  s += __shfl_xor(s,4);
    s += __shfl_xor(s,8); s += __shfl_xor(s,16); s += __shfl_xor(s,32);
    if (lane == 0) xsq[n] = s;
    return;
  }

  if (b == PG_SCAL) {
    // ---- scalars: alpha, q=softmax(q0), cq, tfsq ----
    int t = tid >> 4, l = tid & 15;
    if (tid == 0) walpha[0] = 1.f / (1.f + expf(-alpha0[0]));
    float qr[16]; float mx = -3.0e38f;
#pragma unroll
    for (int m = 0; m < 16; ++m) { qr[m] = q0[t*16+m]; mx = fmaxf(mx, qr[m]); }
    float s = 0.f;
#pragma unroll
    for (int m = 0; m < 16; ++m) { qr[m] = expf(qr[m]-mx); s += qr[m]; }
    float inv = 1.f / s;
    qmat[tid] = qr[l] * inv;
    float c = 0.f;
#pragma unroll
    for (int m = 0; m < 16; ++m) {
      float c2 = templates_[t*256 + l*16 + m];
      c = fmaf(qr[m]*inv, c2*c2, c);
    }
    cq[tid] = c;
    float ts = 0.f;
#pragma unroll
    for (int dq = 0; dq < 32; ++dq) {
      float4 v = *(const float4*)&tf[tid*128 + dq*4];
      ts = fmaf(v.x,v.x,ts); ts = fmaf(v.y,v.y,ts);
      ts = fmaf(v.z,v.z,ts); ts = fmaf(v.w,v.w,ts);
    }
    tfsq[tid] = ts;
    return;
  }
}

// ---------------------------------------------------------------------------
// main: 1 block/node, 256 thr = 16 templates x 16 cols (R9-verbatim, 80.3us
// measured: bitset-L2 prologue + branchy body with volatile pin).
// ---------------------------------------------------------------------------
__global__ __launch_bounds__(256, 2) void ltfgw_main(
    const float* __restrict__ P, const unsigned* __restrict__ adjbits,
    const float* __restrict__ xsq, const float* __restrict__ tfsq,
    const float* __restrict__ qmat, const float* __restrict__ cq,
    const float* __restrict__ walpha, const int* __restrict__ neighbors,
    const float* __restrict__ templates_, float* __restrict__ out) {
  __shared__ __align__(16) float Ksh[16 * TSTR];
  __shared__ __align__(16) float Ush[256];
  __shared__ __align__(16) float Vsh[256];
  __shared__ int nb_sh[20];
  __shared__ int rm_sh[20];

  const int tid = threadIdx.x;
  const int t = tid >> 4, l = tid & 15;
  const int n = blockIdx.x;

  // ---- prologue: build 17 per-row C1 bitmasks from the packed bitset ----
  if (tid < K1) {
    nb_sh[tid] = (tid == 0) ? n : neighbors[n*KNB + tid - 1];
    rm_sh[tid] = 0;
  }
  __syncthreads();
  for (unsigned e = tid; e < 289; e += 256) {
    unsigned i = e / 17u, j = e % 17u;
    int ni = nb_sh[i], nj = nb_sh[j];
    unsigned w = adjbits[ni*128 + (nj >> 5)];
    if ((w >> (nj & 31)) & 1u) atomicOr(&rm_sh[i], 1 << j);
  }
  __syncthreads();

  int rm[K1];
  int nbk[K1];
#pragma unroll
  for (int k = 0; k < K1; ++k) {
    rm[k]  = __builtin_amdgcn_readfirstlane(rm_sh[k]);
    nbk[k] = __builtin_amdgcn_readfirstlane(nb_sh[k]);
  }

  const float alpha = sload(walpha);
  const float oma = 1.f - alpha;
  const float na2 = -2.f * alpha;

  const float tfsq_l = tfsq[tid];
  const float cq_l   = cq[tid];
  const float q_l    = qmat[tid];

  // Mcol = (1-a)*M + a*cC ; cc1 = popcount(row)/17 since C1 is binary.
  float Mcol[K1];
#pragma unroll
  for (int k = 0; k < K1; ++k) {
    float xs  = sload(xsq + nbk[k]);
    float cc1 = (float)__popc((unsigned)rm[k]) * (1.f/17.f);
    float pv  = P[nbk[k]*256 + tid];
    Mcol[k] = oma * (xs + tfsq_l - 2.f*pv) + alpha * (cc1 + cq_l);
  }

  // c2reg[r] = -2a * C2[t][l][l^r]  (pre-rotated for the XOR walk)
  float c2reg[16];
#pragma unroll
  for (int r = 0; r < 16; ++r)
    c2reg[r] = na2 * templates_[t*256 + l*16 + (l ^ r)];

  // G[j][l] in registers; init p*q
  float Gcol[K1];
#pragma unroll
  for (int j = 0; j < K1; ++j) Gcol[j] = (1.f/17.f) * q_l;

  const int tb = t * TSTR;
  float ur[16], u16 = 0.f, vm = 1.f;

#pragma unroll 1
  for (int outer = 0; outer < 3; ++outer) {
    // grad rows -> Kc[]; only C1-nonzero rows (~2.3/17) do bit-sum + walk.
    // The volatile asm pins rmi inside the branch (R7-verified structure).
    float Kc[K1];
    float lo = 3.0e38f, hi = -3.0e38f;
#pragma unroll
    for (int i = 0; i < K1; ++i) {
      float gr = Mcol[i];
      int rmi = rm[i];
      if (rmi) {
        asm volatile("" : "+s"(rmi));
        float s = 0.f;
#pragma unroll
        for (int j = 0; j < K1; ++j)
          if (rmi & (1 << j)) s += Gcol[j];   // == fmaf({0,1},G,s) exactly
        float g = s, acc = s * c2reg[0];
        WALK15()
        gr += acc;
      }
      Kc[i] = gr;
      lo = fminf(lo, gr); hi = fmaxf(hi, gr);
    }
    lo = rmin16(lo); hi = rmax16(hi);
    float eps = 0.1f * (hi - lo) + TINYF;
    float sc = 1.4426950408889634f * __builtin_amdgcn_rcpf(eps);
    float nsc = -sc, losc = lo * sc;
#pragma unroll
    for (int i = 0; i < K1; ++i) {
      Kc[i] = __builtin_amdgcn_exp2f(fmaf(Kc[i], nsc, losc));
      Ksh[tb + i*17 + l] = Kc[i];           // transpose write (same wave)
    }
    // row l of K for the u-update
    float Krow[16];
#pragma unroll
    for (int jq = 0; jq < 4; ++jq) {
      float4 v = *(const float4*)&Ksh[tb + l*17 + jq*4];
      Krow[jq*4+0]=v.x; Krow[jq*4+1]=v.y; Krow[jq*4+2]=v.z; Krow[jq*4+3]=v.w;
    }

    // Sinkhorn: 5 iters (u then v), v0 = 1
    float vlane = 1.f;
    Vsh[tid] = 1.f;
#pragma unroll 1
    for (int it = 0; it < 5; ++it) {
      float vr[16];
#pragma unroll
      for (int q = 0; q < 4; ++q) {
        float4 v = *(const float4*)&Vsh[t*16 + q*4];
        vr[q*4+0]=v.x; vr[q*4+1]=v.y; vr[q*4+2]=v.z; vr[q*4+3]=v.w;
      }
      float w = 0.f;
#pragma unroll
      for (int j = 0; j < 16; ++j) w = fmaf(Krow[j], vr[j], w);
      float w16 = rsum16(Kc[16] * vlane);          // row 16 via DPP
      float um = (1.f/17.f) * rcpn(fmaxf(w,   TINYF));
      u16      = (1.f/17.f) * rcpn(fmaxf(w16, TINYF));
      Ush[tid] = um;
#pragma unroll
      for (int q = 0; q < 4; ++q) {
        float4 v = *(const float4*)&Ush[t*16 + q*4];
        ur[q*4+0]=v.x; ur[q*4+1]=v.y; ur[q*4+2]=v.z; ur[q*4+3]=v.w;
      }
      float sg = u16 * Kc[16];
#pragma unroll
      for (int k = 0; k < 16; ++k) sg = fmaf(ur[k], Kc[k], sg);
      vlane = q_l * rcpn(fmaxf(sg, TINYF));
      Vsh[tid] = vlane;
    }
    vm = vlane;
    // G = u * K * v
#pragma unroll
    for (int k = 0; k < 16; ++k) Gcol[k] = ur[k] * Kc[k] * vm;
    Gcol[16] = u16 * Kc[16] * vm;
  }

  // out[n,t] = sum_{i,l} (Mcol + delta) * G
  float acc1 = 0.f;
#pragma unroll
  for (int i = 0; i < K1; ++i) acc1 = fmaf(Mcol[i], Gcol[i], acc1);
#pragma unroll
  for (int i = 0; i < K1; ++i) {
    int rmi = rm[i];
    if (rmi) {
      asm volatile("" : "+s"(rmi));
      float s = 0.f;
#pragma unroll
      for (int j = 0; j < K1; ++j)
        if (rmi & (1 << j)) s += Gcol[j];
      float g = s, acc = s * c2reg[0];
      WALK15()
      acc1 = fmaf(acc, Gcol[i], acc1);
    }
  }
  float accout = rsum16(acc1);
  if (l == 0) out[n*16 + t] = accout;
}

// ---------------------------------------------------------------------------
extern "C" void kernel_launch(void* const* d_in, const int* in_sizes, int n_in,
                              void* d_out, int out_size, void* d_ws, size_t ws_size,
                              hipStream_t stream) {
  const float* x          = (const float*)d_in[0];
  const float* adj        = (const float*)d_in[1];
  const int*   neighbors  = (const int*)  d_in[2];
  const float* templates_ = (const float*)d_in[3];
  const float* tfeat      = (const float*)d_in[4];
  const float* q0         = (const float*)d_in[5];
  const float* alpha0     = (const float*)d_in[6];
  float* out = (float*)d_out;

  float* ws        = (float*)d_ws;
  float* P         = ws;                         // 4096*256 floats
  unsigned* adjbits = (unsigned*)(P + 4096*256); // 4096*128 u32 = 2 MB
  float* xsq       = (float*)(adjbits + 4096*128);  // 4096
  float* tfsq      = xsq + 4096;                 // 256
  float* qmat      = tfsq + 256;                 // 256
  float* cq        = qmat + 256;                 // 256
  float* walpha    = cq + 256;                   // 1

  hipLaunchKernelGGL(prep_combined, dim3(PG_TOT), dim3(256), 0, stream,
                     x, adj, neighbors, templates_, tfeat, q0, alpha0,
                     P, adjbits, xsq, tfsq, qmat, cq, walpha);
  hipLaunchKernelGGL(ltfgw_main, dim3(4096), dim3(256), 0, stream,
                     P, adjbits, xsq, tfsq, qmat, cq, walpha, neighbors,
                     templates_, out);
}

// Round 11
// 173.315 us; speedup vs baseline: 1.0901x; 1.0433x over previous
//
#include <hip/hip_runtime.h>
#include <math.h>

// ---------------------------------------------------------------------------
// LTFGW: N=4096, K=16 (k1=17), T=16, NT=16, D=128, OUTER=3, INNER=5.
//
// R16 = R13 verbatim (best measured: 174.0us). Terminal configuration after
// 12 experiments. Ledger: total = F(~72-75us harness-fixed) + outside + main;
//   scatter-in-prep: ~110 + 72-76  -> 182-189
//   bitset-prep:     ~97  + 80.3   -> 177-181
//   scatter-in-main: ~82  + 92.2   -> 174.0   <- optimum
// Main's 92us = ~59us VALU latency-chain floor (insensitive to inst count
// across 5 body variants) + ~30us scattered adj-gather drain (153 loads,
// symmetric, overlapped with all barrier-independent work). Every axis
// probed: gather placement x3, gather shape x3, body style x5, pgemm tiling,
// block ordering. Residual is harness-fixed + latency floors.
// ---------------------------------------------------------------------------

#define NN 4096
#define KNB 16
#define K1 17
#define TSTR 296      // Ksh per-template stride; 296%32==8 -> 2-way banks
#define TINYF 1e-16f

typedef const __attribute__((address_space(4))) float* c4fp;
typedef const __attribute__((address_space(4))) int*   c4ip;
__device__ __forceinline__ float sload(const float* p){ return *(c4fp)(unsigned long long)p; }
__device__ __forceinline__ int   sloadi(const int* p) { return *(c4ip)(unsigned long long)p; }

template<int CTRL>
__device__ __forceinline__ float dppmov(float x) {
  return __int_as_float(
      __builtin_amdgcn_update_dpp(0, __float_as_int(x), CTRL, 0xF, 0xF, true));
}
__device__ __forceinline__ float xor4v(float x) {        // xor4 = xor7 then xor3
  return dppmov<0x1B>(dppmov<0x141>(x));
}
__device__ __forceinline__ float rsum16(float x) {
  x += dppmov<0xB1>(x); x += dppmov<0x4E>(x);
  x += xor4v(x);        x += dppmov<0x128>(x);
  return x;
}
__device__ __forceinline__ float rmin16(float x) {
  x = fminf(x, dppmov<0xB1>(x)); x = fminf(x, dppmov<0x4E>(x));
  x = fminf(x, xor4v(x));        x = fminf(x, dppmov<0x128>(x));
  return x;
}
__device__ __forceinline__ float rmax16(float x) {
  x = fmaxf(x, dppmov<0xB1>(x)); x = fmaxf(x, dppmov<0x4E>(x));
  x = fmaxf(x, xor4v(x));        x = fmaxf(x, dppmov<0x128>(x));
  return x;
}
__device__ __forceinline__ float rcpn(float x) {   // rcp + 1 Newton step
  float r = __builtin_amdgcn_rcpf(x);
  return r * (2.f - x * r);
}

// cumulative XOR walk (verified R1/R4, absmax 0): after step r, g = src lane l^r
#define WSTEP(C, R) { g = dppmov<C>(g); acc = fmaf(g, c2reg[R], acc); }
#define WALK15() \
  WSTEP(0xB1,1)  WSTEP(0x1B,2)  WSTEP(0xB1,3)  WSTEP(0x141,4) \
  WSTEP(0xB1,5)  WSTEP(0x1B,6)  WSTEP(0xB1,7)  WSTEP(0x140,8) \
  WSTEP(0xB1,9)  WSTEP(0x1B,10) WSTEP(0xB1,11) WSTEP(0x141,12) \
  WSTEP(0xB1,13) WSTEP(0x1B,14) WSTEP(0xB1,15)

// ---------------------------------------------------------------------------
// prep_combined: one dispatch, block-range partitioned.
//   blocks [0,512)        : pgemm  P = x @ tf^T   (32x64 tile, 2 blocks/CU)
//   blocks [512,1536)     : xsq[n] = ||x[n]||^2   (trivial)
//   block  1536           : scalars (alpha,q,cq,tfsq)
// ---------------------------------------------------------------------------
#define PG_GEMM  512
#define PG_XSQ   (PG_GEMM + 1024)       // 1536
#define PG_SCAL  PG_XSQ                  // block 1536
#define PG_TOT   (PG_SCAL + 1)           // 1537

__global__ __launch_bounds__(256) void prep_combined(
    const float* __restrict__ x,
    const float* __restrict__ templates_,
    const float* __restrict__ tf, const float* __restrict__ q0,
    const float* __restrict__ alpha0,
    float* __restrict__ P,
    float* __restrict__ xsq,
    float* __restrict__ tfsq, float* __restrict__ qmat, float* __restrict__ cq,
    float* __restrict__ walpha) {
  __shared__ __align__(16) float smem[64*36 + 64*68];   // 26624 B arena
  const int b = blockIdx.x, tid = threadIdx.x;

  if (b < PG_GEMM) {
    // ---- pgemm: 32 rows x 64 cols per block, 2x4 per thread ----
    float (*As)[36] = (float (*)[36])smem;            // As[d][row], d<64
    float (*Bs)[68] = (float (*)[68])(smem + 64*36);  // Bs[d][col], d<64
    int tx = tid & 15, ty = tid >> 4;
    int r0 = (b >> 2) * 32, c0 = (b & 3) * 64;
    float acc[2][4] = {};
    for (int h = 0; h < 2; ++h) {
      __syncthreads();
#pragma unroll
      for (int q = 0; q < 2; ++q) {
        int f = tid + 256*q;
        int row = f >> 4, d4 = (f & 15) << 2;
        float4 a = *(const float4*)&x[(r0+row)*128 + h*64 + d4];
        As[d4+0][row]=a.x; As[d4+1][row]=a.y; As[d4+2][row]=a.z; As[d4+3][row]=a.w;
      }
#pragma unroll
      for (int q = 0; q < 4; ++q) {
        int f = tid + 256*q;
        int row = f >> 4, d4 = (f & 15) << 2;
        float4 bb = *(const float4*)&tf[(c0+row)*128 + h*64 + d4];
        Bs[d4+0][row]=bb.x; Bs[d4+1][row]=bb.y; Bs[d4+2][row]=bb.z; Bs[d4+3][row]=bb.w;
      }
      __syncthreads();
#pragma unroll
      for (int d = 0; d < 64; ++d) {
        float2 a = *(const float2*)&As[d][ty*2];
        float4 bb = *(const float4*)&Bs[d][tx*4];
        float av[2]={a.x,a.y}, bv[4]={bb.x,bb.y,bb.z,bb.w};
#pragma unroll
        for (int i = 0; i < 2; ++i)
#pragma unroll
          for (int j = 0; j < 4; ++j) acc[i][j] = fmaf(av[i], bv[j], acc[i][j]);
      }
    }
#pragma unroll
    for (int i = 0; i < 2; ++i) {
      float4 o; o.x=acc[i][0]; o.y=acc[i][1]; o.z=acc[i][2]; o.w=acc[i][3];
      *(float4*)&P[(r0 + ty*2 + i)*256 + c0 + tx*4] = o;
    }
    return;
  }

  if (b < PG_XSQ) {
    // ---- xsq: 4 rows per block, 1 wave per row ----
    int n = (b - PG_GEMM)*4 + (tid >> 6), lane = tid & 63;
    float2 v = *(const float2*)&x[n*128 + lane*2];
    float s = fmaf(v.x, v.x, v.y*v.y);
    s += __shfl_xor(s,1); s += __shfl_xor(s,2);  s += __shfl_xor(s,4);
    s += __shfl_xor(s,8); s += __shfl_xor(s,16); s += __shfl_xor(s,32);
    if (lane == 0) xsq[n] = s;
    return;
  }

  if (b == PG_SCAL) {
    // ---- scalars: alpha, q=softmax(q0), cq, tfsq ----
    int t = tid >> 4, l = tid & 15;
    if (tid == 0) walpha[0] = 1.f / (1.f + expf(-alpha0[0]));
    float qr[16]; float mx = -3.0e38f;
#pragma unroll
    for (int m = 0; m < 16; ++m) { qr[m] = q0[t*16+m]; mx = fmaxf(mx, qr[m]); }
    float s = 0.f;
#pragma unroll
    for (int m = 0; m < 16; ++m) { qr[m] = expf(qr[m]-mx); s += qr[m]; }
    float inv = 1.f / s;
    qmat[tid] = qr[l] * inv;
    float c = 0.f;
#pragma unroll
    for (int m = 0; m < 16; ++m) {
      float c2 = templates_[t*256 + l*16 + m];
      c = fmaf(qr[m]*inv, c2*c2, c);
    }
    cq[tid] = c;
    float ts = 0.f;
#pragma unroll
    for (int dq = 0; dq < 32; ++dq) {
      float4 v = *(const float4*)&tf[tid*128 + dq*4];
      ts = fmaf(v.x,v.x,ts); ts = fmaf(v.y,v.y,ts);
      ts = fmaf(v.z,v.z,ts); ts = fmaf(v.w,v.w,ts);
    }
    tfsq[tid] = ts;
    return;
  }
}

// ---------------------------------------------------------------------------
// main: 1 block/node, 256 thr = 16 templates x 16 cols.
// Prologue: software-pipelined symmetric gather — 153 upper-triangle adj
// loads (1/thread) issued first; nbk sloads + 17 P-row prefetches + c2reg/
// scalar loads + Gcol init overlap the latency; atomicOr + one barrier.
// ---------------------------------------------------------------------------
__global__ __launch_bounds__(256, 2) void ltfgw_main(
    const float* __restrict__ P, const float* __restrict__ adj,
    const float* __restrict__ xsq, const float* __restrict__ tfsq,
    const float* __restrict__ qmat, const float* __restrict__ cq,
    const float* __restrict__ walpha, const int* __restrict__ neighbors,
    const float* __restrict__ templates_, float* __restrict__ out) {
  __shared__ __align__(16) float Ksh[16 * TSTR];
  __shared__ __align__(16) float Ush[256];
  __shared__ __align__(16) float Vsh[256];
  __shared__ int rm_sh[20];

  const int tid = threadIdx.x;
  const int t = tid >> 4, l = tid & 15;
  const int n = blockIdx.x;

  // ---- zero masks; cheap barrier (nothing in flight yet) ----
  if (tid < 20) rm_sh[tid] = 0;
  __syncthreads();

  // ---- issue the C1 gather: upper triangle only (C1 symmetric) ----
  // e = i*17+j over {j>=i}: 150 elements have e<256 (own tid); the 3 with
  // e>=256 are remapped onto idle lower-triangle threads.
  int e = tid;
  if (tid == 17)      e = 15*17 + 15;
  else if (tid == 34) e = 15*17 + 16;
  else if (tid == 51) e = 16*17 + 16;
  const int gi = e / 17, gj = e % 17;
  const bool gact = (gj >= gi);
  float gv = 0.f;
  if (gact) {
    int ni = (gi == 0) ? n : neighbors[n*KNB + gi - 1];
    int nj = (gj == 0) ? n : neighbors[n*KNB + gj - 1];
    gv = adj[(long long)ni * NN + nj];      // {0.0f, 1.0f} exactly
  }

  // ---- overlap: everything that doesn't need the masks ----
  int nbk[K1];
  nbk[0] = n;
#pragma unroll
  for (int k = 1; k < K1; ++k) nbk[k] = sloadi(neighbors + n*KNB + (k-1));

  const float alpha = sload(walpha);
  const float oma = 1.f - alpha;
  const float na2 = -2.f * alpha;

  const float tfsq_l = tfsq[tid];
  const float cq_l   = cq[tid];
  const float q_l    = qmat[tid];

  // prefetch the 17 P values (the other big latency chain)
  float pv[K1];
#pragma unroll
  for (int k = 0; k < K1; ++k) pv[k] = P[nbk[k]*256 + tid];

  // c2reg[r] = -2a * C2[t][l][l^r]  (pre-rotated for the XOR walk)
  float c2reg[16];
#pragma unroll
  for (int r = 0; r < 16; ++r)
    c2reg[r] = na2 * templates_[t*256 + l*16 + (l ^ r)];

  // G[j][l] in registers; init p*q
  float Gcol[K1];
#pragma unroll
  for (int j = 0; j < K1; ++j) Gcol[j] = (1.f/17.f) * q_l;

  // ---- commit gather bits (both halves of the symmetric pair) ----
  if (gact && gv != 0.f) {
    atomicOr(&rm_sh[gi], 1 << gj);
    if (gi != gj) atomicOr(&rm_sh[gj], 1 << gi);
  }
  __syncthreads();

  int rm[K1];
#pragma unroll
  for (int k = 0; k < K1; ++k)
    rm[k] = __builtin_amdgcn_readfirstlane(rm_sh[k]);

  // Mcol = (1-a)*M + a*cC ; cc1 = popcount(row)/17 (C1 binary). Formula
  // bit-identical to R10; pv[] prefetched above.
  float Mcol[K1];
#pragma unroll
  for (int k = 0; k < K1; ++k) {
    float xs  = sload(xsq + nbk[k]);
    float cc1 = (float)__popc((unsigned)rm[k]) * (1.f/17.f);
    Mcol[k] = oma * (xs + tfsq_l - 2.f*pv[k]) + alpha * (cc1 + cq_l);
  }

  const int tb = t * TSTR;
  float ur[16], u16 = 0.f, vm = 1.f;

#pragma unroll 1
  for (int outer = 0; outer < 3; ++outer) {
    // grad rows -> Kc[]; only C1-nonzero rows do bit-sum + walk.
    // Volatile asm pins rmi inside the branch (R7-verified structure).
    float Kc[K1];
    float lo = 3.0e38f, hi = -3.0e38f;
#pragma unroll
    for (int i = 0; i < K1; ++i) {
      float gr = Mcol[i];
      int rmi = rm[i];
      if (rmi) {
        asm volatile("" : "+s"(rmi));
        float s = 0.f;
#pragma unroll
        for (int j = 0; j < K1; ++j)
          if (rmi & (1 << j)) s += Gcol[j];   // == fmaf({0,1},G,s) exactly
        float g = s, acc = s * c2reg[0];
        WALK15()
        gr += acc;
      }
      Kc[i] = gr;
      lo = fminf(lo, gr); hi = fmaxf(hi, gr);
    }
    lo = rmin16(lo); hi = rmax16(hi);
    float eps = 0.1f * (hi - lo) + TINYF;
    float sc = 1.4426950408889634f * __builtin_amdgcn_rcpf(eps);
    float nsc = -sc, losc = lo * sc;
#pragma unroll
    for (int i = 0; i < K1; ++i) {
      Kc[i] = __builtin_amdgcn_exp2f(fmaf(Kc[i], nsc, losc));
      Ksh[tb + i*17 + l] = Kc[i];           // transpose write (same wave)
    }
    // row l of K for the u-update
    float Krow[16];
#pragma unroll
    for (int jq = 0; jq < 4; ++jq) {
      float4 v = *(const float4*)&Ksh[tb + l*17 + jq*4];
      Krow[jq*4+0]=v.x; Krow[jq*4+1]=v.y; Krow[jq*4+2]=v.z; Krow[jq*4+3]=v.w;
    }

    // Sinkhorn: 5 iters (u then v), v0 = 1
    float vlane = 1.f;
    Vsh[tid] = 1.f;
#pragma unroll 1
    for (int it = 0; it < 5; ++it) {
      float vr[16];
#pragma unroll
      for (int q = 0; q < 4; ++q) {
        float4 v = *(const float4*)&Vsh[t*16 + q*4];
        vr[q*4+0]=v.x; vr[q*4+1]=v.y; vr[q*4+2]=v.z; vr[q*4+3]=v.w;
      }
      float w = 0.f;
#pragma unroll
      for (int j = 0; j < 16; ++j) w = fmaf(Krow[j], vr[j], w);
      float w16 = rsum16(Kc[16] * vlane);          // row 16 via DPP
      float um = (1.f/17.f) * rcpn(fmaxf(w,   TINYF));
      u16      = (1.f/17.f) * rcpn(fmaxf(w16, TINYF));
      Ush[tid] = um;
#pragma unroll
      for (int q = 0; q < 4; ++q) {
        float4 v = *(const float4*)&Ush[t*16 + q*4];
        ur[q*4+0]=v.x; ur[q*4+1]=v.y; ur[q*4+2]=v.z; ur[q*4+3]=v.w;
      }
      float sg = u16 * Kc[16];
#pragma unroll
      for (int k = 0; k < 16; ++k) sg = fmaf(ur[k], Kc[k], sg);
      vlane = q_l * rcpn(fmaxf(sg, TINYF));
      Vsh[tid] = vlane;
    }
    vm = vlane;
    // G = u * K * v
#pragma unroll
    for (int k = 0; k < 16; ++k) Gcol[k] = ur[k] * Kc[k] * vm;
    Gcol[16] = u16 * Kc[16] * vm;
  }

  // out[n,t] = sum_{i,l} (Mcol + delta) * G
  float acc1 = 0.f;
#pragma unroll
  for (int i = 0; i < K1; ++i) acc1 = fmaf(Mcol[i], Gcol[i], acc1);
#pragma unroll
  for (int i = 0; i < K1; ++i) {
    int rmi = rm[i];
    if (rmi) {
      asm volatile("" : "+s"(rmi));
      float s = 0.f;
#pragma unroll
      for (int j = 0; j < K1; ++j)
        if (rmi & (1 << j)) s += Gcol[j];
      float g = s, acc = s * c2reg[0];
      WALK15()
      acc1 = fmaf(acc, Gcol[i], acc1);
    }
  }
  float accout = rsum16(acc1);
  if (l == 0) out[n*16 + t] = accout;
}

// ---------------------------------------------------------------------------
extern "C" void kernel_launch(void* const* d_in, const int* in_sizes, int n_in,
                              void* d_out, int out_size, void* d_ws, size_t ws_size,
                              hipStream_t stream) {
  const float* x          = (const float*)d_in[0];
  const float* adj        = (const float*)d_in[1];
  const int*   neighbors  = (const int*)  d_in[2];
  const float* templates_ = (const float*)d_in[3];
  const float* tfeat      = (const float*)d_in[4];
  const float* q0         = (const float*)d_in[5];
  const float* alpha0     = (const float*)d_in[6];
  float* out = (float*)d_out;

  float* ws     = (float*)d_ws;
  float* P      = ws;                       // 4096*256 floats
  float* xsq    = P + 4096*256;             // 4096
  float* tfsq   = xsq + 4096;               // 256
  float* qmat   = tfsq + 256;               // 256
  float* cq     = qmat + 256;               // 256
  float* walpha = cq + 256;                 // 1

  hipLaunchKernelGGL(prep_combined, dim3(PG_TOT), dim3(256), 0, stream,
                     x, templates_, tfeat, q0, alpha0,
                     P, xsq, tfsq, qmat, cq, walpha);
  hipLaunchKernelGGL(ltfgw_main, dim3(4096), dim3(256), 0, stream,
                     P, adj, xsq, tfsq, qmat, cq, walpha, neighbors,
                     templates_, out);
}